// Round 7
// baseline (10401.688 us; speedup 1.0000x reference)
//
#include <hip/hip_runtime.h>
#include <math.h>

// ---------------------------------------------------------------------------
// GCN: h1 = relu(norm_agg(x@W1)+b1); h2 = norm_agg(h1@W2)+b2;
//      g = mean_pool(h2, batch); out = relu(g@W3+b3)@W4 + b4
// R14 algebra (one GEMM, same as R13): norm_agg(x@W) = norm_agg_raw(x)@W;
// pooling commutes with @W2+b2; relu commutes with positive row scale.
//   P = x*dinv[row]   (fused into k_bsort -- block already holds dinv)
//   B = aggS(P): B[d] = (sum_{src->d} P[src] + P[d]) * dinv[d]
//   A = relu(B@W1+b1)*dinv[row]  (fused GEMM epilogue)
//   gsum += pool( (sum A[src] + A[d]) * dinv[d] )
//   head: m@W2+b2 -> relu(@W3+b3) -> @W4+b4
// Agg: ONE wave per 16-dst task (6250 fronts -- measured L2-traffic sweet
// spot: 103/129/180 MB @ 3125/6250/12500 fronts). R14: __launch_bounds__
// (128,4) lifts the VGPR cap (R13 compiled at 32 VGPR = chunked pipeline)
// + explicit 2-round software pipeline: rows of round r+1 and indices of
// round r+2 issued before accumulating round r (~4x in-flight bytes).
// k_bsort: wave-parallel 128-bin scan (was 128 serial LDS round-trips at
// t==0, ~25 us across the grid) + fused prescale.
// ---------------------------------------------------------------------------

#define NBLK 3125  // (100000+31)/32; guarded generically below

__global__ __launch_bounds__(256) void k_init(float* gsum, int* blockCnt,
                                              int gsz, int nblk) {
  int i = blockIdx.x * 256 + threadIdx.x;
  if (i < gsz) gsum[i] = 0.f;
  if (i < nblk + 64) blockCnt[i] = 0;
}

// Histogram of dst>>5 into nblk bins via LDS (12.8 KB), merged to global.
__global__ __launch_bounds__(256) void k_histB(const int* __restrict__ dst,
                                               int* __restrict__ blockCnt,
                                               int e, int nblk) {
  __shared__ int h[3200];
  int t = threadIdx.x;
  for (int i = t; i < 3200; i += 256) h[i] = 0;
  __syncthreads();
  int base = blockIdx.x * 8192;
#pragma unroll
  for (int k = 0; k < 32; ++k) {
    int i = base + k * 256 + t;
    if (i < e) atomicAdd(&h[dst[i] >> 5], 1);
  }
  __syncthreads();
  for (int i = t; i < nblk; i += 256) {
    int v = h[i];
    if (v) atomicAdd(&blockCnt[i], v);
  }
}

// Single-block exclusive scan of blockCnt[nblk]; barrier-light (~2 barriers).
__global__ __launch_bounds__(256) void k_scan(const int* __restrict__ blockCnt,
                                              int* __restrict__ blockBase,
                                              int* __restrict__ blockCursor,
                                              int* __restrict__ bucketCursor,
                                              int nblk, int nbuck) {
  __shared__ int wsum[4];
  int t = threadIdx.x;
  int w = t >> 6, lane = t & 63;
  int ch = (nblk + 255) >> 8;  // chunk per thread (13 for nblk=3125)
  int lo = t * ch;
  int hi = lo + ch;
  if (hi > nblk) hi = nblk;
  int s = 0;
  for (int i = lo; i < hi; ++i) s += blockCnt[i];
  int inc = s;
  for (int off = 1; off < 64; off <<= 1) {
    int u = __shfl_up(inc, off);
    if (lane >= off) inc += u;
  }
  if (lane == 63) wsum[w] = inc;
  __syncthreads();
  int wpre = 0;
  for (int i = 0; i < w; ++i) wpre += wsum[i];
  int run = wpre + inc - s;  // exclusive prefix for this thread's chunk
  for (int i = lo; i < hi; ++i) {
    int v = blockCnt[i];
    blockBase[i] = run;
    blockCursor[i] = run;
    if ((i & 63) == 0 && (i >> 6) < nbuck) bucketCursor[i >> 6] = run;
    run += v;
  }
  if (t == 0) blockBase[nblk] = wsum[0] + wsum[1] + wsum[2] + wsum[3];
}

// Pass 1: bin edges into coarse buckets (2048 nodes each) with range-dense
// writes. Entry = (dstLow6<<22) | (src<<5) | dstLocal.
__global__ __launch_bounds__(256) void k_p1(const int* __restrict__ src,
                                            const int* __restrict__ dst,
                                            int* __restrict__ bucketCursor,
                                            int* __restrict__ tmp, int e) {
  __shared__ int hist[64];
  __shared__ int gbase[64];
  int t = threadIdx.x;
  int base = blockIdx.x * 2048;
  if (t < 64) hist[t] = 0;
  __syncthreads();
  int ent[8], rk[8], bk[8];
#pragma unroll
  for (int k = 0; k < 8; ++k) {
    int i = base + k * 256 + t;
    bool v = i < e;
    int s = v ? src[i] : 0;
    int d = v ? dst[i] : 0;
    bk[k] = d >> 11;
    ent[k] = (((d >> 5) & 63) << 22) | (s << 5) | (d & 31);
    rk[k] = v ? atomicAdd(&hist[bk[k]], 1) : -1;
  }
  __syncthreads();
  if (t < 64 && hist[t] > 0) gbase[t] = atomicAdd(&bucketCursor[t], hist[t]);
  __syncthreads();
#pragma unroll
  for (int k = 0; k < 8; ++k)
    if (rk[k] >= 0) tmp[gbase[bk[k]] + rk[k]] = ent[k];
}

// Pass 2: within each bucket (8 slices/bucket), bin entries to their dst-block
// segment (64 bins), range-dense writes; strip top 6 bits for final csr.
__global__ __launch_bounds__(256) void k_p2(const int* __restrict__ blockBase,
                                            const int* __restrict__ tmp,
                                            int* __restrict__ blockCursor,
                                            int* __restrict__ csr, int nblk) {
  __shared__ int hist[64];
  __shared__ int gbase[64];
  int b = blockIdx.x >> 3;
  int sl = blockIdx.x & 7;
  int hiIdx = (b + 1) << 6;
  if (hiIdx > nblk) hiIdx = nblk;
  int lo_b = blockBase[b << 6];
  int hi_b = blockBase[hiIdx];
  int len = hi_b - lo_b;
  int lo = lo_b + (int)(((long long)len * sl) >> 3);
  int hi = lo_b + (int)(((long long)len * (sl + 1)) >> 3);
  int t = threadIdx.x;
  for (int rbase = lo; rbase < hi; rbase += 2048) {
    if (t < 64) hist[t] = 0;
    __syncthreads();
    int ent[8], rk[8], bin[8];
#pragma unroll
    for (int k = 0; k < 8; ++k) {
      int i = rbase + k * 256 + t;
      bool v = i < hi;
      int en = v ? tmp[i] : 0;
      ent[k] = en;
      bin[k] = en >> 22;
      rk[k] = v ? atomicAdd(&hist[bin[k]], 1) : -1;
    }
    __syncthreads();
    if (t < 64 && hist[t] > 0)
      gbase[t] = atomicAdd(&blockCursor[(b << 6) + t], hist[t]);
    __syncthreads();
#pragma unroll
    for (int k = 0; k < 8; ++k)
      if (rk[k] >= 0) csr[gbase[bin[k]] + rk[k]] = ent[k] & 0x3FFFFF;
    __syncthreads();
  }
}

// Per-node-block (32 dsts): count degrees -> dinv; FUSED prescale
// P[node] = x[node]*dinv[node]; then counting-sort the packed segment by
// (dst-bit4, src>>11) -- EXACT partition into two 16-dst halves (+ src
// locality). Emits per-16-task [segLo,segHi). Oversize segments (>1024)
// keep unsplit defaults; k_agg's dst-bit4 filter keeps it correct.
// 128-bin scan is wave-parallel (shfl), not serial at t==0.
__global__ __launch_bounds__(256) void k_bsort(const int* __restrict__ blockBase,
                                               int* __restrict__ csr,
                                               float* __restrict__ dinv,
                                               int* __restrict__ segLo,
                                               int* __restrict__ segHi,
                                               const float* __restrict__ x,
                                               float* __restrict__ P, int n) {
  __shared__ int in_sh[1024];
  __shared__ int out_sh[1024];
  __shared__ int hist[128];
  __shared__ int hscan[128];
  __shared__ int deg[32];
  __shared__ float sdinv[32];
  int blk = blockIdx.x;
  int nodeBase = blk << 5;
  if (nodeBase >= n) return;
  int p0 = blockBase[blk];
  int p1 = blockBase[blk + 1];
  int seg = p1 - p0;
  int t = threadIdx.x;
  if (t < 32) deg[t] = 0;
  if (t == 0) {  // unsplit defaults (fallback; overwritten if sorted)
    segLo[2 * blk] = p0;
    segHi[2 * blk] = p1;
    segLo[2 * blk + 1] = p0;
    segHi[2 * blk + 1] = p1;
  }
  __syncthreads();
  for (int i = t; i < seg; i += 256) atomicAdd(&deg[csr[p0 + i] & 31], 1);
  __syncthreads();
  if (t < 32 && nodeBase + t < n) {
    float dv = 1.0f / sqrtf((float)(deg[t] + 1));
    dinv[nodeBase + t] = dv;
    sdinv[t] = dv;
  }
  __syncthreads();
  // fused prescale: P[32x64] = x * sdinv[row]  (512 float4, 2/thread)
  for (int i = t; i < 512; i += 256) {
    int row = i >> 4, c4 = (i & 15) << 2;
    int node = nodeBase + row;
    if (node < n) {
      float4 v = *(const float4*)&x[(size_t)node * 64 + c4];
      float sdv = sdinv[row];
      v.x *= sdv; v.y *= sdv; v.z *= sdv; v.w *= sdv;
      *(float4*)&P[(size_t)node * 64 + c4] = v;
    }
  }
  if (seg <= 0 || seg > 1024) return;  // block-uniform
  if (t < 128) hist[t] = 0;
  __syncthreads();
  for (int i = t; i < seg; i += 256) {
    int v = csr[p0 + i];
    in_sh[i] = v;
    // bin = dstBit4*64 + src>>11
    atomicAdd(&hist[((v & 16) << 2) | ((v >> 16) & 63)], 1);
  }
  __syncthreads();
  // wave-parallel exclusive scan of hist[128]: wave 0, lane l owns bins 2l,2l+1
  if (t < 64) {
    int h0 = hist[2 * t], h1 = hist[2 * t + 1];
    int s = h0 + h1;
    int inc = s;
    for (int off = 1; off < 64; off <<= 1) {
      int u = __shfl_up(inc, off);
      if (t >= off) inc += u;
    }
    hscan[2 * t] = inc - s;
    hscan[2 * t + 1] = inc - s + h0;
  }
  __syncthreads();
  int cntLow = hscan[64];  // exact count of dst-bit4==0 entries
  __syncthreads();         // all reads of hscan[64] before scatter mutates it
  for (int i = t; i < seg; i += 256) {
    int v = in_sh[i];
    int pos = atomicAdd(&hscan[((v & 16) << 2) | ((v >> 16) & 63)], 1);
    out_sh[pos] = v;
  }
  __syncthreads();
  for (int i = t; i < seg; i += 256) csr[p0 + i] = out_sh[i];
  if (t == 0) {  // split boundaries (partition is exact)
    segHi[2 * blk] = p0 + cntLow;
    segLo[2 * blk + 1] = p0 + cntLow;
  }
}

// Y[N,64] = relu(X[N,64] @ W[64,64] + bias) * dinv[row]
// (fused bias+relu+scale epilogue; output pre-scaled for layer-2 agg).
__global__ __launch_bounds__(256) void k_gemm64brs(const float* __restrict__ X,
                                                   const float* __restrict__ W,
                                                   const float* __restrict__ bias,
                                                   const float* __restrict__ dinv,
                                                   float* __restrict__ Y, int n) {
  __shared__ float Xs[64 * 65];
  __shared__ float Ws[64 * 64];
  int t = threadIdx.x;
  int r0 = blockIdx.x << 6;
  for (int i = t * 4; i < 4096; i += 1024)
    *(float4*)&Ws[i] = *(const float4*)&W[i];
  for (int s = t; s < 1024; s += 256) {
    int r = s >> 4, c4 = (s & 15) << 2;
    float4 v = make_float4(0.f, 0.f, 0.f, 0.f);
    if (r0 + r < n) v = *(const float4*)&X[(size_t)(r0 + r) * 64 + c4];
    Xs[r * 65 + c4 + 0] = v.x;
    Xs[r * 65 + c4 + 1] = v.y;
    Xs[r * 65 + c4 + 2] = v.z;
    Xs[r * 65 + c4 + 3] = v.w;
  }
  __syncthreads();
  int c4 = (t & 15) << 2;
  int rb = (t >> 4) << 2;
  float4 a0 = {0, 0, 0, 0}, a1 = {0, 0, 0, 0}, a2 = {0, 0, 0, 0}, a3 = {0, 0, 0, 0};
  for (int k = 0; k < 64; ++k) {
    float4 w = *(const float4*)&Ws[k * 64 + c4];
    float x0 = Xs[(rb + 0) * 65 + k];
    float x1 = Xs[(rb + 1) * 65 + k];
    float x2 = Xs[(rb + 2) * 65 + k];
    float x3 = Xs[(rb + 3) * 65 + k];
    a0.x += x0 * w.x; a0.y += x0 * w.y; a0.z += x0 * w.z; a0.w += x0 * w.w;
    a1.x += x1 * w.x; a1.y += x1 * w.y; a1.z += x1 * w.z; a1.w += x1 * w.w;
    a2.x += x2 * w.x; a2.y += x2 * w.y; a2.z += x2 * w.z; a2.w += x2 * w.w;
    a3.x += x3 * w.x; a3.y += x3 * w.y; a3.z += x3 * w.z; a3.w += x3 * w.w;
  }
  float4 bb = *(const float4*)&bias[c4];
  int r = r0 + rb;
  if (r + 0 < n) {
    float s0 = dinv[r + 0];
    a0.x = fmaxf(a0.x + bb.x, 0.f) * s0; a0.y = fmaxf(a0.y + bb.y, 0.f) * s0;
    a0.z = fmaxf(a0.z + bb.z, 0.f) * s0; a0.w = fmaxf(a0.w + bb.w, 0.f) * s0;
    *(float4*)&Y[(size_t)(r + 0) * 64 + c4] = a0;
  }
  if (r + 1 < n) {
    float s1 = dinv[r + 1];
    a1.x = fmaxf(a1.x + bb.x, 0.f) * s1; a1.y = fmaxf(a1.y + bb.y, 0.f) * s1;
    a1.z = fmaxf(a1.z + bb.z, 0.f) * s1; a1.w = fmaxf(a1.w + bb.w, 0.f) * s1;
    *(float4*)&Y[(size_t)(r + 1) * 64 + c4] = a1;
  }
  if (r + 2 < n) {
    float s2 = dinv[r + 2];
    a2.x = fmaxf(a2.x + bb.x, 0.f) * s2; a2.y = fmaxf(a2.y + bb.y, 0.f) * s2;
    a2.z = fmaxf(a2.z + bb.z, 0.f) * s2; a2.w = fmaxf(a2.w + bb.w, 0.f) * s2;
    *(float4*)&Y[(size_t)(r + 2) * 64 + c4] = a2;
  }
  if (r + 3 < n) {
    float s3 = dinv[r + 3];
    a3.x = fmaxf(a3.x + bb.x, 0.f) * s3; a3.y = fmaxf(a3.y + bb.y, 0.f) * s3;
    a3.z = fmaxf(a3.z + bb.z, 0.f) * s3; a3.w = fmaxf(a3.w + bb.w, 0.f) * s3;
    *(float4*)&Y[(size_t)(r + 3) * 64 + c4] = a3;
  }
}

// Aggregation (R14): one wave per 16-dst task, exclusive 4 KB acc. Explicit
// 2-round software pipeline: while accumulating round r, rows of round r+1
// and csr indices of round r+2 are in flight. __launch_bounds__(128,4) lifts
// the VGPR cap (R13's default compiled to 32 VGPR = chunked pipeline).
// Operand rows PRE-SCALED by dinv[src]. out[d] = (acc + X[d]) * dinv[d].
// POOL=0: plain store; POOL=1: atomicAdd into gsum.
template <int POOL>
__global__ __launch_bounds__(128, 4) void k_agg(
    const float* __restrict__ X, const int* __restrict__ csr,
    const int* __restrict__ segLo, const int* __restrict__ segHi,
    const float* __restrict__ dinv, const int* __restrict__ batch,
    float* __restrict__ outv, float* __restrict__ gsum, int n, int ntask) {
  __shared__ float accs[2][16 * 64];  // 8 KB / block
  int t = threadIdx.x;
  int w = t >> 6, lane = t & 63;
  int task = blockIdx.x * 2 + w;
  if (task >= ntask) return;  // wave-uniform; no block syncs below
  int nodeBase = task << 4;
  int par = task & 1;  // dst bit4 owned by this task
  float* a = accs[w];
#pragma unroll 4
  for (int d = 0; d < 16; ++d) a[d * 64 + lane] = 0.f;
  int p0 = segLo[task];
  int p1 = segHi[task];
  int c = p1 - p0;
  if (c > 0) {
    int sub = lane & 31;
    int qlast = p1 - 1;
    int qq0 = p0 + sub;
    int pk = csr[qq0 < qlast ? qq0 : qlast];  // idx round 0
    int qq1 = p0 + 32 + sub;
    int pk1 = (c > 32) ? csr[qq1 < qlast ? qq1 : qlast] : pk;  // idx round 1
    int eec[32];
    float tvc[32];
#pragma unroll
    for (int k = 0; k < 32; ++k) {
      eec[k] = __builtin_amdgcn_readlane(pk, k);
      tvc[k] = X[(size_t)(eec[k] >> 5) * 64 + lane];
    }
    for (int rb = 0; rb < c; rb += 32) {
      // issue csr for round rb+64
      int pk2 = pk1;
      if (rb + 64 < c) {
        int qn = p0 + rb + 64 + sub;
        pk2 = csr[qn < qlast ? qn : qlast];
      }
      // issue rows for round rb+32
      bool morerows = (rb + 32) < c;  // wave-uniform
      int een[32];
      float tvn[32];
      if (morerows) {
#pragma unroll
        for (int k = 0; k < 32; ++k) {
          een[k] = __builtin_amdgcn_readlane(pk1, k);
          tvn[k] = X[(size_t)(een[k] >> 5) * 64 + lane];
        }
      }
      // accumulate current round (wave-uniform predicates)
      int rem = c - rb;
#pragma unroll
      for (int k = 0; k < 32; ++k)
        if (k < rem && (((eec[k] >> 4) & 1) == par))
          a[(eec[k] & 15) * 64 + lane] += tvc[k];
      // shift pipeline
      if (morerows) {
#pragma unroll
        for (int k = 0; k < 32; ++k) {
          eec[k] = een[k];
          tvc[k] = tvn[k];
        }
        pk1 = pk2;
      }
    }
  }
  for (int d = 0; d < 16; ++d) {
    int node = nodeBase + d;
    if (node >= n) break;
    float dn = dinv[node];
    float v = (a[d * 64 + lane] + X[(size_t)node * 64 + lane]) * dn;
    if (POOL) {
      int g = batch[node];
      atomicAdd(&gsum[(size_t)g * 64 + lane], v);
    } else {
      outv[(size_t)node * 64 + lane] = v;
    }
  }
}

// Head: per-graph wave. m = gsum/cnt; g2 = m@W2+b2; g3 = relu(g2@W3+b3);
// out = g3@W4 + b4. Node count via binary search on sorted batch.
__global__ __launch_bounds__(256) void k_head(
    const float* __restrict__ gsum, const int* __restrict__ batch,
    const float* __restrict__ W2, const float* __restrict__ b2,
    const float* __restrict__ W3, const float* __restrict__ b3,
    const float* __restrict__ W4, const float* __restrict__ b4,
    float* __restrict__ out, int ng, int n) {
  int wid = (blockIdx.x * 256 + threadIdx.x) >> 6;
  int lane = threadIdx.x & 63;
  if (wid >= ng) return;
  int lo = 0, hi = n;
  while (lo < hi) {
    int mid = (lo + hi) >> 1;
    if (batch[mid] < wid) lo = mid + 1; else hi = mid;
  }
  int lb = lo;
  hi = n;
  while (lo < hi) {
    int mid = (lo + hi) >> 1;
    if (batch[mid] <= wid) lo = mid + 1; else hi = mid;
  }
  float cden = fmaxf((float)(lo - lb), 1.0f);
  float m = gsum[(size_t)wid * 64 + lane] / cden;
  float g2 = b2[lane];
  for (int k = 0; k < 64; ++k) {
    float mk = __shfl(m, k);
    g2 += mk * W2[k * 64 + lane];
  }
  float g3 = b3[lane];
  for (int k = 0; k < 64; ++k) {
    float gk = __shfl(g2, k);
    g3 += gk * W3[k * 64 + lane];
  }
  g3 = fmaxf(g3, 0.f);
  float r = g3 * W4[lane];
  for (int off = 32; off; off >>= 1) r += __shfl_down(r, off);
  if (lane == 0) out[wid] = r + b4[0];
}

extern "C" void kernel_launch(void* const* d_in, const int* in_sizes, int n_in,
                              void* d_out, int out_size, void* d_ws, size_t ws_size,
                              hipStream_t stream) {
  const float* x = (const float*)d_in[0];
  const int* edge = (const int*)d_in[1];   // [2, E] int32
  const int* batch = (const int*)d_in[2];  // [N] int32, sorted
  const float* W1 = (const float*)d_in[3];
  const float* b1 = (const float*)d_in[4];
  const float* W2 = (const float*)d_in[5];
  const float* b2 = (const float*)d_in[6];
  const float* W3 = (const float*)d_in[7];
  const float* b3 = (const float*)d_in[8];
  const float* W4 = (const float*)d_in[9];
  const float* b4 = (const float*)d_in[10];
  float* out = (float*)d_out;

  const int n = in_sizes[0] / 64;   // 100000
  const int e = in_sizes[1] / 2;    // 1600000
  const int ng = out_size;          // 512
  const int* src = edge;
  const int* dst = edge + e;

  // Workspace layout.
  char* ws = (char*)d_ws;
  size_t off = 0;
  auto alloc = [&](size_t bytes) -> void* {
    void* p = ws + off;
    off = (off + bytes + 255) & ~(size_t)255;
    return p;
  };
  float* A = (float*)alloc((size_t)n * 64 * 4);   // P (prescaled x), then h1*dinv
  float* B = (float*)alloc((size_t)n * 64 * 4);   // agg1 out; tmp during build
  float* dinv = (float*)alloc((size_t)n * 4);
  int* blockCnt = (int*)alloc(3264 * 4);
  int* blockBase = (int*)alloc(3264 * 4);
  int* blockCursor = (int*)alloc(3264 * 4);
  int* bucketCursor = (int*)alloc(64 * 4);
  int* segLo = (int*)alloc(6400 * 4);
  int* segHi = (int*)alloc(6400 * 4);
  int* csr = (int*)alloc((size_t)e * 4);
  float* gsum = (float*)alloc((size_t)ng * 64 * 4);
  int* tmp = (int*)B;  // build-time only; B not live yet

  const int nblk = (n + 31) / 32;        // 3125 dst-blocks
  const int nbuck = (nblk + 63) / 64;    // 49 coarse buckets
  const int ntask = 2 * nblk;            // 6250 16-dst agg tasks
  const int nagg = (ntask + 1) / 2;      // agg workgroups (3125): 2 tasks/blk
  const int gsz = ng * 64;

  int zmax = gsz > nblk + 64 ? gsz : nblk + 64;
  k_init<<<(zmax + 255) / 256, 256, 0, stream>>>(gsum, blockCnt, gsz, nblk);
  k_histB<<<(e + 8191) / 8192, 256, 0, stream>>>(dst, blockCnt, e, nblk);
  k_scan<<<1, 256, 0, stream>>>(blockCnt, blockBase, blockCursor, bucketCursor,
                                nblk, nbuck);
  k_p1<<<(e + 2047) / 2048, 256, 0, stream>>>(src, dst, bucketCursor, tmp, e);
  k_p2<<<nbuck * 8, 256, 0, stream>>>(blockBase, tmp, blockCursor, csr, nblk);
  // bsort: dinv + exact 16-dst partition + FUSED prescale (A = x*dinv[row])
  k_bsort<<<nblk, 256, 0, stream>>>(blockBase, csr, dinv, segLo, segHi, x, A, n);

  // Layer 1: B = aggS(A)
  k_agg<0><<<nagg, 128, 0, stream>>>(A, csr, segLo, segHi, dinv, batch, B,
                                     gsum, n, ntask);
  // A = relu(B@W1 + b1) * dinv[row]
  k_gemm64brs<<<(n + 63) / 64, 256, 0, stream>>>(B, W1, b1, dinv, A, n);
  // Layer 2: gsum += pooled aggS(A)
  k_agg<1><<<nagg, 128, 0, stream>>>(A, csr, segLo, segHi, dinv, batch, B,
                                     gsum, n, ntask);
  // Head: mean, @W2+b2, relu(@W3+b3), @W4+b4
  k_head<<<((size_t)ng * 64 + 255) / 256, 256, 0, stream>>>(
      gsum, batch, W2, b2, W3, b3, W4, b4, out, ng, n);
}

// Round 8
// 315.525 us; speedup vs baseline: 32.9663x; 32.9663x over previous
//
#include <hip/hip_runtime.h>
#include <math.h>

// ---------------------------------------------------------------------------
// GCN: h1 = relu(norm_agg(x@W1)+b1); h2 = norm_agg(h1@W2)+b2;
//      g = mean_pool(h2, batch); out = relu(g@W3+b3)@W4 + b4
// R15 algebra (one GEMM): norm_agg(x@W) = norm_agg_raw(x)@W; pooling commutes
// with @W2+b2; relu commutes with positive row scale.
//   P = x*dinv[row]   (fused into k_bsort -- block already holds dinv)
//   B = aggS(P): B[d] = (sum_{src->d} P[src] + P[d]) * dinv[d]
//   A = relu(B@W1+b1)*dinv[row]  (fused GEMM epilogue)
//   gsum += pool( (sum A[src] + A[d]) * dinv[d] )
//   head: m@W2+b2 -> relu(@W3+b3) -> @W4+b4
// Agg = R13's EXACT hot loop (proven 65 us): one wave per 16-dst task (6250
// fronts -- measured L2-traffic sweet spot 103/129/180 MB @ 3125/6250/12500
// fronts), plain rounds-of-32 with index prefetch, compiler-scheduled.
// R14 lesson: forcing deeper reg pipelines (launch_bounds(128,4) + 2-round
// explicit pipeline) spilled ~128 regs of state to scratch -> 13.8 GB writes,
// 80x slower. VGPR=32 chunked schedule IS the floor for this loop.
// k_bsort: wave-parallel 128-bin scan + fused prescale (saves a kernel).
// ---------------------------------------------------------------------------

#define NBLK 3125  // (100000+31)/32; guarded generically below

__global__ __launch_bounds__(256) void k_init(float* gsum, int* blockCnt,
                                              int gsz, int nblk) {
  int i = blockIdx.x * 256 + threadIdx.x;
  if (i < gsz) gsum[i] = 0.f;
  if (i < nblk + 64) blockCnt[i] = 0;
}

// Histogram of dst>>5 into nblk bins via LDS (12.8 KB), merged to global.
__global__ __launch_bounds__(256) void k_histB(const int* __restrict__ dst,
                                               int* __restrict__ blockCnt,
                                               int e, int nblk) {
  __shared__ int h[3200];
  int t = threadIdx.x;
  for (int i = t; i < 3200; i += 256) h[i] = 0;
  __syncthreads();
  int base = blockIdx.x * 8192;
#pragma unroll
  for (int k = 0; k < 32; ++k) {
    int i = base + k * 256 + t;
    if (i < e) atomicAdd(&h[dst[i] >> 5], 1);
  }
  __syncthreads();
  for (int i = t; i < nblk; i += 256) {
    int v = h[i];
    if (v) atomicAdd(&blockCnt[i], v);
  }
}

// Single-block exclusive scan of blockCnt[nblk]; barrier-light (~2 barriers).
__global__ __launch_bounds__(256) void k_scan(const int* __restrict__ blockCnt,
                                              int* __restrict__ blockBase,
                                              int* __restrict__ blockCursor,
                                              int* __restrict__ bucketCursor,
                                              int nblk, int nbuck) {
  __shared__ int wsum[4];
  int t = threadIdx.x;
  int w = t >> 6, lane = t & 63;
  int ch = (nblk + 255) >> 8;  // chunk per thread (13 for nblk=3125)
  int lo = t * ch;
  int hi = lo + ch;
  if (hi > nblk) hi = nblk;
  int s = 0;
  for (int i = lo; i < hi; ++i) s += blockCnt[i];
  int inc = s;
  for (int off = 1; off < 64; off <<= 1) {
    int u = __shfl_up(inc, off);
    if (lane >= off) inc += u;
  }
  if (lane == 63) wsum[w] = inc;
  __syncthreads();
  int wpre = 0;
  for (int i = 0; i < w; ++i) wpre += wsum[i];
  int run = wpre + inc - s;  // exclusive prefix for this thread's chunk
  for (int i = lo; i < hi; ++i) {
    int v = blockCnt[i];
    blockBase[i] = run;
    blockCursor[i] = run;
    if ((i & 63) == 0 && (i >> 6) < nbuck) bucketCursor[i >> 6] = run;
    run += v;
  }
  if (t == 0) blockBase[nblk] = wsum[0] + wsum[1] + wsum[2] + wsum[3];
}

// Pass 1: bin edges into coarse buckets (2048 nodes each) with range-dense
// writes. Entry = (dstLow6<<22) | (src<<5) | dstLocal.
__global__ __launch_bounds__(256) void k_p1(const int* __restrict__ src,
                                            const int* __restrict__ dst,
                                            int* __restrict__ bucketCursor,
                                            int* __restrict__ tmp, int e) {
  __shared__ int hist[64];
  __shared__ int gbase[64];
  int t = threadIdx.x;
  int base = blockIdx.x * 2048;
  if (t < 64) hist[t] = 0;
  __syncthreads();
  int ent[8], rk[8], bk[8];
#pragma unroll
  for (int k = 0; k < 8; ++k) {
    int i = base + k * 256 + t;
    bool v = i < e;
    int s = v ? src[i] : 0;
    int d = v ? dst[i] : 0;
    bk[k] = d >> 11;
    ent[k] = (((d >> 5) & 63) << 22) | (s << 5) | (d & 31);
    rk[k] = v ? atomicAdd(&hist[bk[k]], 1) : -1;
  }
  __syncthreads();
  if (t < 64 && hist[t] > 0) gbase[t] = atomicAdd(&bucketCursor[t], hist[t]);
  __syncthreads();
#pragma unroll
  for (int k = 0; k < 8; ++k)
    if (rk[k] >= 0) tmp[gbase[bk[k]] + rk[k]] = ent[k];
}

// Pass 2: within each bucket (8 slices/bucket), bin entries to their dst-block
// segment (64 bins), range-dense writes; strip top 6 bits for final csr.
__global__ __launch_bounds__(256) void k_p2(const int* __restrict__ blockBase,
                                            const int* __restrict__ tmp,
                                            int* __restrict__ blockCursor,
                                            int* __restrict__ csr, int nblk) {
  __shared__ int hist[64];
  __shared__ int gbase[64];
  int b = blockIdx.x >> 3;
  int sl = blockIdx.x & 7;
  int hiIdx = (b + 1) << 6;
  if (hiIdx > nblk) hiIdx = nblk;
  int lo_b = blockBase[b << 6];
  int hi_b = blockBase[hiIdx];
  int len = hi_b - lo_b;
  int lo = lo_b + (int)(((long long)len * sl) >> 3);
  int hi = lo_b + (int)(((long long)len * (sl + 1)) >> 3);
  int t = threadIdx.x;
  for (int rbase = lo; rbase < hi; rbase += 2048) {
    if (t < 64) hist[t] = 0;
    __syncthreads();
    int ent[8], rk[8], bin[8];
#pragma unroll
    for (int k = 0; k < 8; ++k) {
      int i = rbase + k * 256 + t;
      bool v = i < hi;
      int en = v ? tmp[i] : 0;
      ent[k] = en;
      bin[k] = en >> 22;
      rk[k] = v ? atomicAdd(&hist[bin[k]], 1) : -1;
    }
    __syncthreads();
    if (t < 64 && hist[t] > 0)
      gbase[t] = atomicAdd(&blockCursor[(b << 6) + t], hist[t]);
    __syncthreads();
#pragma unroll
    for (int k = 0; k < 8; ++k)
      if (rk[k] >= 0) csr[gbase[bin[k]] + rk[k]] = ent[k] & 0x3FFFFF;
    __syncthreads();
  }
}

// Per-node-block (32 dsts): count degrees -> dinv; FUSED prescale
// P[node] = x[node]*dinv[node]; then counting-sort the packed segment by
// (dst-bit4, src>>11) -- EXACT partition into two 16-dst halves (+ src
// locality). Emits per-16-task [segLo,segHi). Oversize segments (>1024)
// keep unsplit defaults; k_agg's dst-bit4 filter keeps it correct.
// 128-bin scan is wave-parallel (shfl), not serial at t==0.
__global__ __launch_bounds__(256) void k_bsort(const int* __restrict__ blockBase,
                                               int* __restrict__ csr,
                                               float* __restrict__ dinv,
                                               int* __restrict__ segLo,
                                               int* __restrict__ segHi,
                                               const float* __restrict__ x,
                                               float* __restrict__ P, int n) {
  __shared__ int in_sh[1024];
  __shared__ int out_sh[1024];
  __shared__ int hist[128];
  __shared__ int hscan[128];
  __shared__ int deg[32];
  __shared__ float sdinv[32];
  int blk = blockIdx.x;
  int nodeBase = blk << 5;
  if (nodeBase >= n) return;
  int p0 = blockBase[blk];
  int p1 = blockBase[blk + 1];
  int seg = p1 - p0;
  int t = threadIdx.x;
  if (t < 32) deg[t] = 0;
  if (t == 0) {  // unsplit defaults (fallback; overwritten if sorted)
    segLo[2 * blk] = p0;
    segHi[2 * blk] = p1;
    segLo[2 * blk + 1] = p0;
    segHi[2 * blk + 1] = p1;
  }
  __syncthreads();
  for (int i = t; i < seg; i += 256) atomicAdd(&deg[csr[p0 + i] & 31], 1);
  __syncthreads();
  if (t < 32 && nodeBase + t < n) {
    float dv = 1.0f / sqrtf((float)(deg[t] + 1));
    dinv[nodeBase + t] = dv;
    sdinv[t] = dv;
  }
  __syncthreads();
  // fused prescale: P[32x64] = x * sdinv[row]  (512 float4, 2/thread)
  for (int i = t; i < 512; i += 256) {
    int row = i >> 4, c4 = (i & 15) << 2;
    int node = nodeBase + row;
    if (node < n) {
      float4 v = *(const float4*)&x[(size_t)node * 64 + c4];
      float sdv = sdinv[row];
      v.x *= sdv; v.y *= sdv; v.z *= sdv; v.w *= sdv;
      *(float4*)&P[(size_t)node * 64 + c4] = v;
    }
  }
  if (seg <= 0 || seg > 1024) return;  // block-uniform
  if (t < 128) hist[t] = 0;
  __syncthreads();
  for (int i = t; i < seg; i += 256) {
    int v = csr[p0 + i];
    in_sh[i] = v;
    // bin = dstBit4*64 + src>>11
    atomicAdd(&hist[((v & 16) << 2) | ((v >> 16) & 63)], 1);
  }
  __syncthreads();
  // wave-parallel exclusive scan of hist[128]: wave 0, lane l owns bins 2l,2l+1
  if (t < 64) {
    int h0 = hist[2 * t], h1 = hist[2 * t + 1];
    int s = h0 + h1;
    int inc = s;
    for (int off = 1; off < 64; off <<= 1) {
      int u = __shfl_up(inc, off);
      if (t >= off) inc += u;
    }
    hscan[2 * t] = inc - s;
    hscan[2 * t + 1] = inc - s + h0;
  }
  __syncthreads();
  int cntLow = hscan[64];  // exact count of dst-bit4==0 entries
  __syncthreads();         // all reads of hscan[64] before scatter mutates it
  for (int i = t; i < seg; i += 256) {
    int v = in_sh[i];
    int pos = atomicAdd(&hscan[((v & 16) << 2) | ((v >> 16) & 63)], 1);
    out_sh[pos] = v;
  }
  __syncthreads();
  for (int i = t; i < seg; i += 256) csr[p0 + i] = out_sh[i];
  if (t == 0) {  // split boundaries (partition is exact)
    segHi[2 * blk] = p0 + cntLow;
    segLo[2 * blk + 1] = p0 + cntLow;
  }
}

// Y[N,64] = relu(X[N,64] @ W[64,64] + bias) * dinv[row]
// (fused bias+relu+scale epilogue; output pre-scaled for layer-2 agg).
__global__ __launch_bounds__(256) void k_gemm64brs(const float* __restrict__ X,
                                                   const float* __restrict__ W,
                                                   const float* __restrict__ bias,
                                                   const float* __restrict__ dinv,
                                                   float* __restrict__ Y, int n) {
  __shared__ float Xs[64 * 65];
  __shared__ float Ws[64 * 64];
  int t = threadIdx.x;
  int r0 = blockIdx.x << 6;
  for (int i = t * 4; i < 4096; i += 1024)
    *(float4*)&Ws[i] = *(const float4*)&W[i];
  for (int s = t; s < 1024; s += 256) {
    int r = s >> 4, c4 = (s & 15) << 2;
    float4 v = make_float4(0.f, 0.f, 0.f, 0.f);
    if (r0 + r < n) v = *(const float4*)&X[(size_t)(r0 + r) * 64 + c4];
    Xs[r * 65 + c4 + 0] = v.x;
    Xs[r * 65 + c4 + 1] = v.y;
    Xs[r * 65 + c4 + 2] = v.z;
    Xs[r * 65 + c4 + 3] = v.w;
  }
  __syncthreads();
  int c4 = (t & 15) << 2;
  int rb = (t >> 4) << 2;
  float4 a0 = {0, 0, 0, 0}, a1 = {0, 0, 0, 0}, a2 = {0, 0, 0, 0}, a3 = {0, 0, 0, 0};
  for (int k = 0; k < 64; ++k) {
    float4 w = *(const float4*)&Ws[k * 64 + c4];
    float x0 = Xs[(rb + 0) * 65 + k];
    float x1 = Xs[(rb + 1) * 65 + k];
    float x2 = Xs[(rb + 2) * 65 + k];
    float x3 = Xs[(rb + 3) * 65 + k];
    a0.x += x0 * w.x; a0.y += x0 * w.y; a0.z += x0 * w.z; a0.w += x0 * w.w;
    a1.x += x1 * w.x; a1.y += x1 * w.y; a1.z += x1 * w.z; a1.w += x1 * w.w;
    a2.x += x2 * w.x; a2.y += x2 * w.y; a2.z += x2 * w.z; a2.w += x2 * w.w;
    a3.x += x3 * w.x; a3.y += x3 * w.y; a3.z += x3 * w.z; a3.w += x3 * w.w;
  }
  float4 bb = *(const float4*)&bias[c4];
  int r = r0 + rb;
  if (r + 0 < n) {
    float s0 = dinv[r + 0];
    a0.x = fmaxf(a0.x + bb.x, 0.f) * s0; a0.y = fmaxf(a0.y + bb.y, 0.f) * s0;
    a0.z = fmaxf(a0.z + bb.z, 0.f) * s0; a0.w = fmaxf(a0.w + bb.w, 0.f) * s0;
    *(float4*)&Y[(size_t)(r + 0) * 64 + c4] = a0;
  }
  if (r + 1 < n) {
    float s1 = dinv[r + 1];
    a1.x = fmaxf(a1.x + bb.x, 0.f) * s1; a1.y = fmaxf(a1.y + bb.y, 0.f) * s1;
    a1.z = fmaxf(a1.z + bb.z, 0.f) * s1; a1.w = fmaxf(a1.w + bb.w, 0.f) * s1;
    *(float4*)&Y[(size_t)(r + 1) * 64 + c4] = a1;
  }
  if (r + 2 < n) {
    float s2 = dinv[r + 2];
    a2.x = fmaxf(a2.x + bb.x, 0.f) * s2; a2.y = fmaxf(a2.y + bb.y, 0.f) * s2;
    a2.z = fmaxf(a2.z + bb.z, 0.f) * s2; a2.w = fmaxf(a2.w + bb.w, 0.f) * s2;
    *(float4*)&Y[(size_t)(r + 2) * 64 + c4] = a2;
  }
  if (r + 3 < n) {
    float s3 = dinv[r + 3];
    a3.x = fmaxf(a3.x + bb.x, 0.f) * s3; a3.y = fmaxf(a3.y + bb.y, 0.f) * s3;
    a3.z = fmaxf(a3.z + bb.z, 0.f) * s3; a3.w = fmaxf(a3.w + bb.w, 0.f) * s3;
    *(float4*)&Y[(size_t)(r + 3) * 64 + c4] = a3;
  }
}

// Aggregation (R15 = R13's exact hot loop): one wave per 16-dst task,
// exclusive 4 KB acc, rounds of 32 with index prefetch; operand rows are
// PRE-SCALED by dinv[src]. out[d] = (acc + X[d]) * dinv[d]. 128-thr blocks
// (2 tasks). POOL=0: plain store; POOL=1: atomicAdd into gsum.
template <int POOL>
__global__ __launch_bounds__(128) void k_agg(
    const float* __restrict__ X, const int* __restrict__ csr,
    const int* __restrict__ segLo, const int* __restrict__ segHi,
    const float* __restrict__ dinv, const int* __restrict__ batch,
    float* __restrict__ outv, float* __restrict__ gsum, int n, int ntask) {
  __shared__ float accs[2][16 * 64];  // 8 KB / block
  int t = threadIdx.x;
  int w = t >> 6, lane = t & 63;
  int task = blockIdx.x * 2 + w;
  if (task >= ntask) return;  // wave-uniform; no block syncs below
  int nodeBase = task << 4;
  int par = task & 1;  // dst bit4 owned by this task
  float* a = accs[w];
#pragma unroll 4
  for (int d = 0; d < 16; ++d) a[d * 64 + lane] = 0.f;
  int p0 = segLo[task];
  int p1 = segHi[task];
  int c = p1 - p0;
  if (c > 0) {
    int sub = lane & 31;
    int qlast = p1 - 1;
    int qq = p0 + sub;
    int pk = csr[qq < qlast ? qq : qlast];  // round-0 indices (32 in lanes)
    for (int rb = 0; rb < c; rb += 32) {
      int pk_next = 0;
      bool more = (rb + 32) < c;  // wave-uniform
      if (more) {
        int qn = p0 + rb + 32 + sub;
        pk_next = csr[qn < qlast ? qn : qlast];  // prefetch next round
      }
      int rem = c - rb;  // wave-uniform
      int ee[32];
#pragma unroll
      for (int k = 0; k < 32; ++k) ee[k] = __builtin_amdgcn_readlane(pk, k);
      // branch-free batch of 32 independent gathers (clamped dups at tail)
      float tv[32];
#pragma unroll
      for (int k = 0; k < 32; ++k)
        tv[k] = X[(size_t)(ee[k] >> 5) * 64 + lane];
      // guarded accumulates (wave-uniform predicates)
#pragma unroll
      for (int k = 0; k < 32; ++k)
        if (k < rem && (((ee[k] >> 4) & 1) == par))
          a[(ee[k] & 15) * 64 + lane] += tv[k];
      pk = pk_next;
    }
  }
  for (int d = 0; d < 16; ++d) {
    int node = nodeBase + d;
    if (node >= n) break;
    float dn = dinv[node];
    float v = (a[d * 64 + lane] + X[(size_t)node * 64 + lane]) * dn;
    if (POOL) {
      int g = batch[node];
      atomicAdd(&gsum[(size_t)g * 64 + lane], v);
    } else {
      outv[(size_t)node * 64 + lane] = v;
    }
  }
}

// Head: per-graph wave. m = gsum/cnt; g2 = m@W2+b2; g3 = relu(g2@W3+b3);
// out = g3@W4 + b4. Node count via binary search on sorted batch.
__global__ __launch_bounds__(256) void k_head(
    const float* __restrict__ gsum, const int* __restrict__ batch,
    const float* __restrict__ W2, const float* __restrict__ b2,
    const float* __restrict__ W3, const float* __restrict__ b3,
    const float* __restrict__ W4, const float* __restrict__ b4,
    float* __restrict__ out, int ng, int n) {
  int wid = (blockIdx.x * 256 + threadIdx.x) >> 6;
  int lane = threadIdx.x & 63;
  if (wid >= ng) return;
  int lo = 0, hi = n;
  while (lo < hi) {
    int mid = (lo + hi) >> 1;
    if (batch[mid] < wid) lo = mid + 1; else hi = mid;
  }
  int lb = lo;
  hi = n;
  while (lo < hi) {
    int mid = (lo + hi) >> 1;
    if (batch[mid] <= wid) lo = mid + 1; else hi = mid;
  }
  float cden = fmaxf((float)(lo - lb), 1.0f);
  float m = gsum[(size_t)wid * 64 + lane] / cden;
  float g2 = b2[lane];
  for (int k = 0; k < 64; ++k) {
    float mk = __shfl(m, k);
    g2 += mk * W2[k * 64 + lane];
  }
  float g3 = b3[lane];
  for (int k = 0; k < 64; ++k) {
    float gk = __shfl(g2, k);
    g3 += gk * W3[k * 64 + lane];
  }
  g3 = fmaxf(g3, 0.f);
  float r = g3 * W4[lane];
  for (int off = 32; off; off >>= 1) r += __shfl_down(r, off);
  if (lane == 0) out[wid] = r + b4[0];
}

extern "C" void kernel_launch(void* const* d_in, const int* in_sizes, int n_in,
                              void* d_out, int out_size, void* d_ws, size_t ws_size,
                              hipStream_t stream) {
  const float* x = (const float*)d_in[0];
  const int* edge = (const int*)d_in[1];   // [2, E] int32
  const int* batch = (const int*)d_in[2];  // [N] int32, sorted
  const float* W1 = (const float*)d_in[3];
  const float* b1 = (const float*)d_in[4];
  const float* W2 = (const float*)d_in[5];
  const float* b2 = (const float*)d_in[6];
  const float* W3 = (const float*)d_in[7];
  const float* b3 = (const float*)d_in[8];
  const float* W4 = (const float*)d_in[9];
  const float* b4 = (const float*)d_in[10];
  float* out = (float*)d_out;

  const int n = in_sizes[0] / 64;   // 100000
  const int e = in_sizes[1] / 2;    // 1600000
  const int ng = out_size;          // 512
  const int* src = edge;
  const int* dst = edge + e;

  // Workspace layout.
  char* ws = (char*)d_ws;
  size_t off = 0;
  auto alloc = [&](size_t bytes) -> void* {
    void* p = ws + off;
    off = (off + bytes + 255) & ~(size_t)255;
    return p;
  };
  float* A = (float*)alloc((size_t)n * 64 * 4);   // P (prescaled x), then h1*dinv
  float* B = (float*)alloc((size_t)n * 64 * 4);   // agg1 out; tmp during build
  float* dinv = (float*)alloc((size_t)n * 4);
  int* blockCnt = (int*)alloc(3264 * 4);
  int* blockBase = (int*)alloc(3264 * 4);
  int* blockCursor = (int*)alloc(3264 * 4);
  int* bucketCursor = (int*)alloc(64 * 4);
  int* segLo = (int*)alloc(6400 * 4);
  int* segHi = (int*)alloc(6400 * 4);
  int* csr = (int*)alloc((size_t)e * 4);
  float* gsum = (float*)alloc((size_t)ng * 64 * 4);
  int* tmp = (int*)B;  // build-time only; B not live yet

  const int nblk = (n + 31) / 32;        // 3125 dst-blocks
  const int nbuck = (nblk + 63) / 64;    // 49 coarse buckets
  const int ntask = 2 * nblk;            // 6250 16-dst agg tasks
  const int nagg = (ntask + 1) / 2;      // agg workgroups (3125): 2 tasks/blk
  const int gsz = ng * 64;

  int zmax = gsz > nblk + 64 ? gsz : nblk + 64;
  k_init<<<(zmax + 255) / 256, 256, 0, stream>>>(gsum, blockCnt, gsz, nblk);
  k_histB<<<(e + 8191) / 8192, 256, 0, stream>>>(dst, blockCnt, e, nblk);
  k_scan<<<1, 256, 0, stream>>>(blockCnt, blockBase, blockCursor, bucketCursor,
                                nblk, nbuck);
  k_p1<<<(e + 2047) / 2048, 256, 0, stream>>>(src, dst, bucketCursor, tmp, e);
  k_p2<<<nbuck * 8, 256, 0, stream>>>(blockBase, tmp, blockCursor, csr, nblk);
  // bsort: dinv + exact 16-dst partition + FUSED prescale (A = x*dinv[row])
  k_bsort<<<nblk, 256, 0, stream>>>(blockBase, csr, dinv, segLo, segHi, x, A, n);

  // Layer 1: B = aggS(A)
  k_agg<0><<<nagg, 128, 0, stream>>>(A, csr, segLo, segHi, dinv, batch, B,
                                     gsum, n, ntask);
  // A = relu(B@W1 + b1) * dinv[row]
  k_gemm64brs<<<(n + 63) / 64, 256, 0, stream>>>(B, W1, b1, dinv, A, n);
  // Layer 2: gsum += pooled aggS(A)
  k_agg<1><<<nagg, 128, 0, stream>>>(A, csr, segLo, segHi, dinv, batch, B,
                                     gsum, n, ntask);
  // Head: mean, @W2+b2, relu(@W3+b3), @W4+b4
  k_head<<<((size_t)ng * 64 + 255) / 256, 256, 0, stream>>>(
      gsum, batch, W2, b2, W3, b3, W4, b4, out, ng, n);
}

// Round 9
// 305.530 us; speedup vs baseline: 34.0447x; 1.0327x over previous
//
#include <hip/hip_runtime.h>
#include <hip/hip_fp16.h>
#include <math.h>

// ---------------------------------------------------------------------------
// GCN: h1 = relu(norm_agg(x@W1)+b1); h2 = norm_agg(h1@W2)+b2;
//      g = mean_pool(h2, batch); out = relu(g@W3+b3)@W4 + b4
// R16 algebra (one GEMM, = R15): norm_agg(x@W) = norm_agg_raw(x)@W; pooling
// commutes with @W2+b2; relu commutes with positive row scale.
//   P16 = fp16(x*dinv[row])          (fused into k_bsort)
//   B   = aggS(P16): B[d] = (sum_{src->d} P[src] + P[d]) * dinv[d]   (fp32)
//   A16 = fp16(relu(B@W1+b1)*dinv[row])   (fused GEMM epilogue)
//   gsum += pool( (sum A16[src] + A16[d]) * dinv[d] )
//   head: m@W2+b2 -> relu(@W3+b3) -> @W4+b4
// R16 change: GATHERED operands are fp16 (row = 128 B, X footprint 12.8 MB)
// -- agg is latency-bound on gather misses (FETCH 129 MB @ 2.4 TB/s = 54 of
// 65 us); halving the footprint doubles the L2-resident share of the
// collective front. LDS accumulate + B + gsum stay fp32; only final 512
// outputs are checked, fp16 rounding contracts to ~1e-5 through the pools.
// Agg config locked by R10-R15: one wave per 16-dst task (6250 fronts --
// FETCH law 103/129/180 MB @ 3125/6250/12500), plain rounds-of-32,
// compiler-scheduled (R14: forcing reg pipelines -> 13.8 GB scratch spill).
// ---------------------------------------------------------------------------

#define NBLK 3125  // (100000+31)/32; guarded generically below

__global__ __launch_bounds__(256) void k_init(float* gsum, int* blockCnt,
                                              int gsz, int nblk) {
  int i = blockIdx.x * 256 + threadIdx.x;
  if (i < gsz) gsum[i] = 0.f;
  if (i < nblk + 64) blockCnt[i] = 0;
}

// Histogram of dst>>5 into nblk bins via LDS (12.8 KB), merged to global.
__global__ __launch_bounds__(256) void k_histB(const int* __restrict__ dst,
                                               int* __restrict__ blockCnt,
                                               int e, int nblk) {
  __shared__ int h[3200];
  int t = threadIdx.x;
  for (int i = t; i < 3200; i += 256) h[i] = 0;
  __syncthreads();
  int base = blockIdx.x * 8192;
#pragma unroll
  for (int k = 0; k < 32; ++k) {
    int i = base + k * 256 + t;
    if (i < e) atomicAdd(&h[dst[i] >> 5], 1);
  }
  __syncthreads();
  for (int i = t; i < nblk; i += 256) {
    int v = h[i];
    if (v) atomicAdd(&blockCnt[i], v);
  }
}

// Single-block exclusive scan of blockCnt[nblk]; barrier-light (~2 barriers).
__global__ __launch_bounds__(256) void k_scan(const int* __restrict__ blockCnt,
                                              int* __restrict__ blockBase,
                                              int* __restrict__ blockCursor,
                                              int* __restrict__ bucketCursor,
                                              int nblk, int nbuck) {
  __shared__ int wsum[4];
  int t = threadIdx.x;
  int w = t >> 6, lane = t & 63;
  int ch = (nblk + 255) >> 8;  // chunk per thread (13 for nblk=3125)
  int lo = t * ch;
  int hi = lo + ch;
  if (hi > nblk) hi = nblk;
  int s = 0;
  for (int i = lo; i < hi; ++i) s += blockCnt[i];
  int inc = s;
  for (int off = 1; off < 64; off <<= 1) {
    int u = __shfl_up(inc, off);
    if (lane >= off) inc += u;
  }
  if (lane == 63) wsum[w] = inc;
  __syncthreads();
  int wpre = 0;
  for (int i = 0; i < w; ++i) wpre += wsum[i];
  int run = wpre + inc - s;  // exclusive prefix for this thread's chunk
  for (int i = lo; i < hi; ++i) {
    int v = blockCnt[i];
    blockBase[i] = run;
    blockCursor[i] = run;
    if ((i & 63) == 0 && (i >> 6) < nbuck) bucketCursor[i >> 6] = run;
    run += v;
  }
  if (t == 0) blockBase[nblk] = wsum[0] + wsum[1] + wsum[2] + wsum[3];
}

// Pass 1: bin edges into coarse buckets (2048 nodes each) with range-dense
// writes. Entry = (dstLow6<<22) | (src<<5) | dstLocal.
__global__ __launch_bounds__(256) void k_p1(const int* __restrict__ src,
                                            const int* __restrict__ dst,
                                            int* __restrict__ bucketCursor,
                                            int* __restrict__ tmp, int e) {
  __shared__ int hist[64];
  __shared__ int gbase[64];
  int t = threadIdx.x;
  int base = blockIdx.x * 2048;
  if (t < 64) hist[t] = 0;
  __syncthreads();
  int ent[8], rk[8], bk[8];
#pragma unroll
  for (int k = 0; k < 8; ++k) {
    int i = base + k * 256 + t;
    bool v = i < e;
    int s = v ? src[i] : 0;
    int d = v ? dst[i] : 0;
    bk[k] = d >> 11;
    ent[k] = (((d >> 5) & 63) << 22) | (s << 5) | (d & 31);
    rk[k] = v ? atomicAdd(&hist[bk[k]], 1) : -1;
  }
  __syncthreads();
  if (t < 64 && hist[t] > 0) gbase[t] = atomicAdd(&bucketCursor[t], hist[t]);
  __syncthreads();
#pragma unroll
  for (int k = 0; k < 8; ++k)
    if (rk[k] >= 0) tmp[gbase[bk[k]] + rk[k]] = ent[k];
}

// Pass 2: within each bucket (8 slices/bucket), bin entries to their dst-block
// segment (64 bins), range-dense writes; strip top 6 bits for final csr.
__global__ __launch_bounds__(256) void k_p2(const int* __restrict__ blockBase,
                                            const int* __restrict__ tmp,
                                            int* __restrict__ blockCursor,
                                            int* __restrict__ csr, int nblk) {
  __shared__ int hist[64];
  __shared__ int gbase[64];
  int b = blockIdx.x >> 3;
  int sl = blockIdx.x & 7;
  int hiIdx = (b + 1) << 6;
  if (hiIdx > nblk) hiIdx = nblk;
  int lo_b = blockBase[b << 6];
  int hi_b = blockBase[hiIdx];
  int len = hi_b - lo_b;
  int lo = lo_b + (int)(((long long)len * sl) >> 3);
  int hi = lo_b + (int)(((long long)len * (sl + 1)) >> 3);
  int t = threadIdx.x;
  for (int rbase = lo; rbase < hi; rbase += 2048) {
    if (t < 64) hist[t] = 0;
    __syncthreads();
    int ent[8], rk[8], bin[8];
#pragma unroll
    for (int k = 0; k < 8; ++k) {
      int i = rbase + k * 256 + t;
      bool v = i < hi;
      int en = v ? tmp[i] : 0;
      ent[k] = en;
      bin[k] = en >> 22;
      rk[k] = v ? atomicAdd(&hist[bin[k]], 1) : -1;
    }
    __syncthreads();
    if (t < 64 && hist[t] > 0)
      gbase[t] = atomicAdd(&blockCursor[(b << 6) + t], hist[t]);
    __syncthreads();
#pragma unroll
    for (int k = 0; k < 8; ++k)
      if (rk[k] >= 0) csr[gbase[bin[k]] + rk[k]] = ent[k] & 0x3FFFFF;
    __syncthreads();
  }
}

// Per-node-block (32 dsts): count degrees -> dinv; FUSED fp16 prescale
// P16[node] = fp16(x[node]*dinv[node]); then counting-sort the packed segment
// by (dst-bit4, src>>11) -- EXACT partition into two 16-dst halves (+ src
// locality). Emits per-16-task [segLo,segHi). Oversize segments (>1024)
// keep unsplit defaults; k_agg's dst-bit4 filter keeps it correct.
// 128-bin scan is wave-parallel (shfl).
__global__ __launch_bounds__(256) void k_bsort(const int* __restrict__ blockBase,
                                               int* __restrict__ csr,
                                               float* __restrict__ dinv,
                                               int* __restrict__ segLo,
                                               int* __restrict__ segHi,
                                               const float* __restrict__ x,
                                               __half* __restrict__ P16, int n) {
  __shared__ int in_sh[1024];
  __shared__ int out_sh[1024];
  __shared__ int hist[128];
  __shared__ int hscan[128];
  __shared__ int deg[32];
  __shared__ float sdinv[32];
  int blk = blockIdx.x;
  int nodeBase = blk << 5;
  if (nodeBase >= n) return;
  int p0 = blockBase[blk];
  int p1 = blockBase[blk + 1];
  int seg = p1 - p0;
  int t = threadIdx.x;
  if (t < 32) deg[t] = 0;
  if (t == 0) {  // unsplit defaults (fallback; overwritten if sorted)
    segLo[2 * blk] = p0;
    segHi[2 * blk] = p1;
    segLo[2 * blk + 1] = p0;
    segHi[2 * blk + 1] = p1;
  }
  __syncthreads();
  for (int i = t; i < seg; i += 256) atomicAdd(&deg[csr[p0 + i] & 31], 1);
  __syncthreads();
  if (t < 32 && nodeBase + t < n) {
    float dv = 1.0f / sqrtf((float)(deg[t] + 1));
    dinv[nodeBase + t] = dv;
    sdinv[t] = dv;
  }
  __syncthreads();
  // fused prescale: P16[32x64] = fp16(x * sdinv[row])  (1024 half2, 4/thread)
  for (int i = t; i < 1024; i += 256) {
    int row = i >> 5, h2 = (i & 31) << 1;
    int node = nodeBase + row;
    if (node < n) {
      float2 v = *(const float2*)&x[(size_t)node * 64 + h2];
      float sdv = sdinv[row];
      *(__half2*)&P16[(size_t)node * 64 + h2] =
          __floats2half2_rn(v.x * sdv, v.y * sdv);
    }
  }
  if (seg <= 0 || seg > 1024) return;  // block-uniform
  if (t < 128) hist[t] = 0;
  __syncthreads();
  for (int i = t; i < seg; i += 256) {
    int v = csr[p0 + i];
    in_sh[i] = v;
    // bin = dstBit4*64 + src>>11
    atomicAdd(&hist[((v & 16) << 2) | ((v >> 16) & 63)], 1);
  }
  __syncthreads();
  // wave-parallel exclusive scan of hist[128]: wave 0, lane l owns bins 2l,2l+1
  if (t < 64) {
    int h0 = hist[2 * t], h1 = hist[2 * t + 1];
    int s = h0 + h1;
    int inc = s;
    for (int off = 1; off < 64; off <<= 1) {
      int u = __shfl_up(inc, off);
      if (t >= off) inc += u;
    }
    hscan[2 * t] = inc - s;
    hscan[2 * t + 1] = inc - s + h0;
  }
  __syncthreads();
  int cntLow = hscan[64];  // exact count of dst-bit4==0 entries
  __syncthreads();         // all reads of hscan[64] before scatter mutates it
  for (int i = t; i < seg; i += 256) {
    int v = in_sh[i];
    int pos = atomicAdd(&hscan[((v & 16) << 2) | ((v >> 16) & 63)], 1);
    out_sh[pos] = v;
  }
  __syncthreads();
  for (int i = t; i < seg; i += 256) csr[p0 + i] = out_sh[i];
  if (t == 0) {  // split boundaries (partition is exact)
    segHi[2 * blk] = p0 + cntLow;
    segLo[2 * blk + 1] = p0 + cntLow;
  }
}

// Y16[N,64] = fp16( relu(X[N,64] @ W[64,64] + bias) * dinv[row] )
// (fused bias+relu+scale+fp16-pack epilogue; output feeds layer-2 agg).
__global__ __launch_bounds__(256) void k_gemm64brs(const float* __restrict__ X,
                                                   const float* __restrict__ W,
                                                   const float* __restrict__ bias,
                                                   const float* __restrict__ dinv,
                                                   __half* __restrict__ Y16, int n) {
  __shared__ float Xs[64 * 65];
  __shared__ float Ws[64 * 64];
  int t = threadIdx.x;
  int r0 = blockIdx.x << 6;
  for (int i = t * 4; i < 4096; i += 1024)
    *(float4*)&Ws[i] = *(const float4*)&W[i];
  for (int s = t; s < 1024; s += 256) {
    int r = s >> 4, c4 = (s & 15) << 2;
    float4 v = make_float4(0.f, 0.f, 0.f, 0.f);
    if (r0 + r < n) v = *(const float4*)&X[(size_t)(r0 + r) * 64 + c4];
    Xs[r * 65 + c4 + 0] = v.x;
    Xs[r * 65 + c4 + 1] = v.y;
    Xs[r * 65 + c4 + 2] = v.z;
    Xs[r * 65 + c4 + 3] = v.w;
  }
  __syncthreads();
  int c4 = (t & 15) << 2;
  int rb = (t >> 4) << 2;
  float4 a0 = {0, 0, 0, 0}, a1 = {0, 0, 0, 0}, a2 = {0, 0, 0, 0}, a3 = {0, 0, 0, 0};
  for (int k = 0; k < 64; ++k) {
    float4 w = *(const float4*)&Ws[k * 64 + c4];
    float x0 = Xs[(rb + 0) * 65 + k];
    float x1 = Xs[(rb + 1) * 65 + k];
    float x2 = Xs[(rb + 2) * 65 + k];
    float x3 = Xs[(rb + 3) * 65 + k];
    a0.x += x0 * w.x; a0.y += x0 * w.y; a0.z += x0 * w.z; a0.w += x0 * w.w;
    a1.x += x1 * w.x; a1.y += x1 * w.y; a1.z += x1 * w.z; a1.w += x1 * w.w;
    a2.x += x2 * w.x; a2.y += x2 * w.y; a2.z += x2 * w.z; a2.w += x2 * w.w;
    a3.x += x3 * w.x; a3.y += x3 * w.y; a3.z += x3 * w.z; a3.w += x3 * w.w;
  }
  float4 bb = *(const float4*)&bias[c4];
  int r = r0 + rb;
  union { __half2 h[2]; uint2 u; } pk;
  if (r + 0 < n) {
    float s0 = dinv[r + 0];
    pk.h[0] = __floats2half2_rn(fmaxf(a0.x + bb.x, 0.f) * s0,
                                fmaxf(a0.y + bb.y, 0.f) * s0);
    pk.h[1] = __floats2half2_rn(fmaxf(a0.z + bb.z, 0.f) * s0,
                                fmaxf(a0.w + bb.w, 0.f) * s0);
    *(uint2*)&Y16[(size_t)(r + 0) * 64 + c4] = pk.u;
  }
  if (r + 1 < n) {
    float s1 = dinv[r + 1];
    pk.h[0] = __floats2half2_rn(fmaxf(a1.x + bb.x, 0.f) * s1,
                                fmaxf(a1.y + bb.y, 0.f) * s1);
    pk.h[1] = __floats2half2_rn(fmaxf(a1.z + bb.z, 0.f) * s1,
                                fmaxf(a1.w + bb.w, 0.f) * s1);
    *(uint2*)&Y16[(size_t)(r + 1) * 64 + c4] = pk.u;
  }
  if (r + 2 < n) {
    float s2 = dinv[r + 2];
    pk.h[0] = __floats2half2_rn(fmaxf(a2.x + bb.x, 0.f) * s2,
                                fmaxf(a2.y + bb.y, 0.f) * s2);
    pk.h[1] = __floats2half2_rn(fmaxf(a2.z + bb.z, 0.f) * s2,
                                fmaxf(a2.w + bb.w, 0.f) * s2);
    *(uint2*)&Y16[(size_t)(r + 2) * 64 + c4] = pk.u;
  }
  if (r + 3 < n) {
    float s3 = dinv[r + 3];
    pk.h[0] = __floats2half2_rn(fmaxf(a3.x + bb.x, 0.f) * s3,
                                fmaxf(a3.y + bb.y, 0.f) * s3);
    pk.h[1] = __floats2half2_rn(fmaxf(a3.z + bb.z, 0.f) * s3,
                                fmaxf(a3.w + bb.w, 0.f) * s3);
    *(uint2*)&Y16[(size_t)(r + 3) * 64 + c4] = pk.u;
  }
}

// Aggregation (R16 = R15 hot loop, fp16 gathers): one wave per 16-dst task,
// exclusive 4 KB fp32 acc, rounds of 32 with index prefetch; operand rows
// are fp16 PRE-SCALED by dinv[src] (128 B/row -> 2x L2-resident front).
// out[d] = (acc + X[d]) * dinv[d]. POOL=0: fp32 store; POOL=1: gsum add.
template <int POOL>
__global__ __launch_bounds__(128) void k_agg(
    const __half* __restrict__ Xh, const int* __restrict__ csr,
    const int* __restrict__ segLo, const int* __restrict__ segHi,
    const float* __restrict__ dinv, const int* __restrict__ batch,
    float* __restrict__ outv, float* __restrict__ gsum, int n, int ntask) {
  __shared__ float accs[2][16 * 64];  // 8 KB / block
  int t = threadIdx.x;
  int w = t >> 6, lane = t & 63;
  int task = blockIdx.x * 2 + w;
  if (task >= ntask) return;  // wave-uniform; no block syncs below
  int nodeBase = task << 4;
  int par = task & 1;  // dst bit4 owned by this task
  float* a = accs[w];
#pragma unroll 4
  for (int d = 0; d < 16; ++d) a[d * 64 + lane] = 0.f;
  int p0 = segLo[task];
  int p1 = segHi[task];
  int c = p1 - p0;
  if (c > 0) {
    int sub = lane & 31;
    int qlast = p1 - 1;
    int qq = p0 + sub;
    int pk = csr[qq < qlast ? qq : qlast];  // round-0 indices (32 in lanes)
    for (int rb = 0; rb < c; rb += 32) {
      int pk_next = 0;
      bool more = (rb + 32) < c;  // wave-uniform
      if (more) {
        int qn = p0 + rb + 32 + sub;
        pk_next = csr[qn < qlast ? qn : qlast];  // prefetch next round
      }
      int rem = c - rb;  // wave-uniform
      int ee[32];
#pragma unroll
      for (int k = 0; k < 32; ++k) ee[k] = __builtin_amdgcn_readlane(pk, k);
      // branch-free batch of 32 independent fp16 gathers (clamped dups)
      __half tv[32];
#pragma unroll
      for (int k = 0; k < 32; ++k)
        tv[k] = Xh[(size_t)(ee[k] >> 5) * 64 + lane];
      // guarded accumulates (wave-uniform predicates), cvt to fp32
#pragma unroll
      for (int k = 0; k < 32; ++k)
        if (k < rem && (((ee[k] >> 4) & 1) == par))
          a[(ee[k] & 15) * 64 + lane] += __half2float(tv[k]);
      pk = pk_next;
    }
  }
  for (int d = 0; d < 16; ++d) {
    int node = nodeBase + d;
    if (node >= n) break;
    float dn = dinv[node];
    float xv = __half2float(Xh[(size_t)node * 64 + lane]);
    float v = (a[d * 64 + lane] + xv) * dn;
    if (POOL) {
      int g = batch[node];
      atomicAdd(&gsum[(size_t)g * 64 + lane], v);
    } else {
      outv[(size_t)node * 64 + lane] = v;
    }
  }
}

// Head: per-graph wave. m = gsum/cnt; g2 = m@W2+b2; g3 = relu(g2@W3+b3);
// out = g3@W4 + b4. Node count via binary search on sorted batch.
__global__ __launch_bounds__(256) void k_head(
    const float* __restrict__ gsum, const int* __restrict__ batch,
    const float* __restrict__ W2, const float* __restrict__ b2,
    const float* __restrict__ W3, const float* __restrict__ b3,
    const float* __restrict__ W4, const float* __restrict__ b4,
    float* __restrict__ out, int ng, int n) {
  int wid = (blockIdx.x * 256 + threadIdx.x) >> 6;
  int lane = threadIdx.x & 63;
  if (wid >= ng) return;
  int lo = 0, hi = n;
  while (lo < hi) {
    int mid = (lo + hi) >> 1;
    if (batch[mid] < wid) lo = mid + 1; else hi = mid;
  }
  int lb = lo;
  hi = n;
  while (lo < hi) {
    int mid = (lo + hi) >> 1;
    if (batch[mid] <= wid) lo = mid + 1; else hi = mid;
  }
  float cden = fmaxf((float)(lo - lb), 1.0f);
  float m = gsum[(size_t)wid * 64 + lane] / cden;
  float g2 = b2[lane];
  for (int k = 0; k < 64; ++k) {
    float mk = __shfl(m, k);
    g2 += mk * W2[k * 64 + lane];
  }
  float g3 = b3[lane];
  for (int k = 0; k < 64; ++k) {
    float gk = __shfl(g2, k);
    g3 += gk * W3[k * 64 + lane];
  }
  g3 = fmaxf(g3, 0.f);
  float r = g3 * W4[lane];
  for (int off = 32; off; off >>= 1) r += __shfl_down(r, off);
  if (lane == 0) out[wid] = r + b4[0];
}

extern "C" void kernel_launch(void* const* d_in, const int* in_sizes, int n_in,
                              void* d_out, int out_size, void* d_ws, size_t ws_size,
                              hipStream_t stream) {
  const float* x = (const float*)d_in[0];
  const int* edge = (const int*)d_in[1];   // [2, E] int32
  const int* batch = (const int*)d_in[2];  // [N] int32, sorted
  const float* W1 = (const float*)d_in[3];
  const float* b1 = (const float*)d_in[4];
  const float* W2 = (const float*)d_in[5];
  const float* b2 = (const float*)d_in[6];
  const float* W3 = (const float*)d_in[7];
  const float* b3 = (const float*)d_in[8];
  const float* W4 = (const float*)d_in[9];
  const float* b4 = (const float*)d_in[10];
  float* out = (float*)d_out;

  const int n = in_sizes[0] / 64;   // 100000
  const int e = in_sizes[1] / 2;    // 1600000
  const int ng = out_size;          // 512
  const int* src = edge;
  const int* dst = edge + e;

  // Workspace layout.
  char* ws = (char*)d_ws;
  size_t off = 0;
  auto alloc = [&](size_t bytes) -> void* {
    void* p = ws + off;
    off = (off + bytes + 255) & ~(size_t)255;
    return p;
  };
  __half* A16 = (__half*)alloc((size_t)n * 64 * 2);  // P16, then h1*dinv fp16
  float* B = (float*)alloc((size_t)n * 64 * 4);      // agg1 out; tmp in build
  float* dinv = (float*)alloc((size_t)n * 4);
  int* blockCnt = (int*)alloc(3264 * 4);
  int* blockBase = (int*)alloc(3264 * 4);
  int* blockCursor = (int*)alloc(3264 * 4);
  int* bucketCursor = (int*)alloc(64 * 4);
  int* segLo = (int*)alloc(6400 * 4);
  int* segHi = (int*)alloc(6400 * 4);
  int* csr = (int*)alloc((size_t)e * 4);
  float* gsum = (float*)alloc((size_t)ng * 64 * 4);
  int* tmp = (int*)B;  // build-time only; B not live yet

  const int nblk = (n + 31) / 32;        // 3125 dst-blocks
  const int nbuck = (nblk + 63) / 64;    // 49 coarse buckets
  const int ntask = 2 * nblk;            // 6250 16-dst agg tasks
  const int nagg = (ntask + 1) / 2;      // agg workgroups (3125): 2 tasks/blk
  const int gsz = ng * 64;

  int zmax = gsz > nblk + 64 ? gsz : nblk + 64;
  k_init<<<(zmax + 255) / 256, 256, 0, stream>>>(gsum, blockCnt, gsz, nblk);
  k_histB<<<(e + 8191) / 8192, 256, 0, stream>>>(dst, blockCnt, e, nblk);
  k_scan<<<1, 256, 0, stream>>>(blockCnt, blockBase, blockCursor, bucketCursor,
                                nblk, nbuck);
  k_p1<<<(e + 2047) / 2048, 256, 0, stream>>>(src, dst, bucketCursor, tmp, e);
  k_p2<<<nbuck * 8, 256, 0, stream>>>(blockBase, tmp, blockCursor, csr, nblk);
  // bsort: dinv + exact 16-dst partition + FUSED fp16 prescale (A16 = x*dinv)
  k_bsort<<<nblk, 256, 0, stream>>>(blockBase, csr, dinv, segLo, segHi, x, A16, n);

  // Layer 1: B = aggS(A16)
  k_agg<0><<<nagg, 128, 0, stream>>>(A16, csr, segLo, segHi, dinv, batch, B,
                                     gsum, n, ntask);
  // A16 = fp16( relu(B@W1 + b1) * dinv[row] )
  k_gemm64brs<<<(n + 63) / 64, 256, 0, stream>>>(B, W1, b1, dinv, A16, n);
  // Layer 2: gsum += pooled aggS(A16)
  k_agg<1><<<nagg, 128, 0, stream>>>(A16, csr, segLo, segHi, dinv, batch, B,
                                     gsum, n, ntask);
  // Head: mean, @W2+b2, relu(@W3+b3), @W4+b4
  k_head<<<((size_t)ng * 64 + 255) / 256, 256, 0, stream>>>(
      gsum, batch, W2, b2, W3, b3, W4, b4, out, ng, n);
}